// Round 1
// baseline (278.390 us; speedup 1.0000x reference)
//
#include <hip/hip_runtime.h>

#define D 1024
#define EPS 1e-5f

// One block per token. 256 threads, 4 elements each.
__global__ __launch_bounds__(256) void emb_deq_ln_kernel(
    const int*   __restrict__ x,       // [T] token ids (int32 from harness)
    const int*   __restrict__ w,       // [V, D] int codes 0..255
    const float* __restrict__ absmax,  // [V*D/4096]; row v uses absmax[v>>2]
    const float* __restrict__ code,    // [256]
    const float* __restrict__ ln_w,    // [D]
    const float* __restrict__ ln_b,    // [D]
    float*       __restrict__ out)     // [T, D]
{
    __shared__ float code_s[256];
    __shared__ float red[8];     // 4 waves x {sum, sumsq}
    __shared__ float stats[2];   // mean, rstd

    const int tid = threadIdx.x;

    // Stage code table into LDS (exactly 256 threads).
    code_s[tid] = code[tid];

    const int t = blockIdx.x;
    const int v = x[t];
    const float scale = absmax[v >> 2];

    // Coalesced 16B load of 4 codes.
    const int4 wq = ((const int4*)(w + (size_t)v * D))[tid];

    __syncthreads();  // code_s ready

    float vals[4];
    vals[0] = code_s[wq.x] * scale;
    vals[1] = code_s[wq.y] * scale;
    vals[2] = code_s[wq.z] * scale;
    vals[3] = code_s[wq.w] * scale;

    float s  = vals[0] + vals[1] + vals[2] + vals[3];
    float ss = vals[0]*vals[0] + vals[1]*vals[1] + vals[2]*vals[2] + vals[3]*vals[3];

    // 64-lane wave reduction
    #pragma unroll
    for (int off = 32; off > 0; off >>= 1) {
        s  += __shfl_down(s,  off, 64);
        ss += __shfl_down(ss, off, 64);
    }
    const int lane = tid & 63;
    const int wid  = tid >> 6;
    if (lane == 0) { red[wid * 2] = s; red[wid * 2 + 1] = ss; }
    __syncthreads();

    if (tid == 0) {
        const float ts  = red[0] + red[2] + red[4] + red[6];
        const float tss = red[1] + red[3] + red[5] + red[7];
        const float mean = ts * (1.0f / D);
        const float var  = tss * (1.0f / D) - mean * mean;
        stats[0] = mean;
        stats[1] = rsqrtf(var + EPS);
    }
    __syncthreads();

    const float mean = stats[0];
    const float rstd = stats[1];

    const float4 lw = ((const float4*)ln_w)[tid];
    const float4 lb = ((const float4*)ln_b)[tid];

    float4 o;
    o.x = (vals[0] - mean) * rstd * lw.x + lb.x;
    o.y = (vals[1] - mean) * rstd * lw.y + lb.y;
    o.z = (vals[2] - mean) * rstd * lw.z + lb.z;
    o.w = (vals[3] - mean) * rstd * lw.w + lb.w;

    ((float4*)(out + (size_t)t * D))[tid] = o;
}

extern "C" void kernel_launch(void* const* d_in, const int* in_sizes, int n_in,
                              void* d_out, int out_size, void* d_ws, size_t ws_size,
                              hipStream_t stream) {
    const int*   x      = (const int*)d_in[0];
    const int*   w      = (const int*)d_in[1];
    const float* absmax = (const float*)d_in[2];
    const float* code   = (const float*)d_in[3];
    const float* ln_w   = (const float*)d_in[4];
    const float* ln_b   = (const float*)d_in[5];
    float* out = (float*)d_out;

    const int T = in_sizes[0];  // 8 * 2048 = 16384 tokens

    emb_deq_ln_kernel<<<T, 256, 0, stream>>>(x, w, absmax, code, ln_w, ln_b, out);
}